// Round 1
// baseline (217.025 us; speedup 1.0000x reference)
//
#include <hip/hip_runtime.h>
#include <math.h>

#define LTOT 64

struct cpx { float r, i; };
struct Mat { cpx e00, e01, e10, e11; };

__device__ __forceinline__ cpx cmul(cpx a, cpx b) {
    return { fmaf(a.r, b.r, -a.i * b.i), fmaf(a.r, b.i, a.i * b.r) };
}
// a*b + c
__device__ __forceinline__ cpx cmadd(cpx a, cpx b, cpx c) {
    return { fmaf(a.r, b.r, fmaf(-a.i, b.i, c.r)),
             fmaf(a.r, b.i, fmaf( a.i, b.r, c.i)) };
}
__device__ __forceinline__ Mat mmul(const Mat& A, const Mat& B) {
    Mat C;
    C.e00 = cmadd(A.e01, B.e10, cmul(A.e00, B.e00));
    C.e01 = cmadd(A.e01, B.e11, cmul(A.e00, B.e01));
    C.e10 = cmadd(A.e11, B.e10, cmul(A.e10, B.e00));
    C.e11 = cmadd(A.e11, B.e11, cmul(A.e10, B.e01));
    return C;
}
// principal sqrt for re>0, im>=0 region (eps_re in [1.8,4.5])
__device__ __forceinline__ cpx csqrt_pos(cpx z) {
    float m  = sqrtf(fmaf(z.r, z.r, z.i * z.i));
    float re = sqrtf(0.5f * (m + z.r));
    float im = 0.5f * z.i / re;
    return { re, im };
}

// one layer: build M and do P = P @ M  (or P = M if first)
__device__ __forceinline__ void accum(Mat& P, bool first, float k0d,
                                      cpx n0, float inv_n0sq, cpx kap, float sgn) {
    float x = fmaf(sgn, kap.r, n0.r) * k0d;   // Re(delta)
    float y = fmaf(sgn, kap.i, n0.i) * k0d;   // Im(delta)
    float sx, cx;
    sincosf(x, &sx, &cx);
    float e  = expf(y);
    float ei = expf(-y);
    float ch = 0.5f * (e + ei);
    float sh = 0.5f * (e - ei);
    cpx cc = { cx * ch, -sx * sh };           // cos(delta)
    cpx ss = { sx * ch,  cx * sh };           // sin(delta)
    // q = s / Y  (Y = n0)
    cpx q  = { (ss.r * n0.r + ss.i * n0.i) * inv_n0sq,
               (ss.i * n0.r - ss.r * n0.i) * inv_n0sq };
    cpx m01 = { -q.i, q.r };                  // i * s / Y
    cpx p   = cmul(n0, ss);
    cpx m10 = { -p.i, p.r };                  // i * Y * s
    if (first) {
        P.e00 = cc; P.e01 = m01; P.e10 = m10; P.e11 = cc;
    } else {
        Mat C;
        C.e00 = cmadd(P.e01, m10, cmul(P.e00, cc));
        C.e01 = cmadd(P.e01, cc,  cmul(P.e00, m01));
        C.e10 = cmadd(P.e11, m10, cmul(P.e10, cc));
        C.e11 = cmadd(P.e11, cc,  cmul(P.e10, m01));
        P = C;
    }
}

__device__ __forceinline__ Mat shfl_mat(const Mat& M, int mask) {
    Mat R;
    R.e00.r = __shfl_xor(M.e00.r, mask); R.e00.i = __shfl_xor(M.e00.i, mask);
    R.e01.r = __shfl_xor(M.e01.r, mask); R.e01.i = __shfl_xor(M.e01.i, mask);
    R.e10.r = __shfl_xor(M.e10.r, mask); R.e10.i = __shfl_xor(M.e10.i, mask);
    R.e11.r = __shfl_xor(M.e11.r, mask); R.e11.i = __shfl_xor(M.e11.i, mask);
    return R;
}

__global__ __launch_bounds__(256) void chiral_kernel(
    const float* __restrict__ wl,  const float* __restrict__ thickP,
    const float* __restrict__ mindp, const float* __restrict__ maxdp,
    const float* __restrict__ ecr, const float* __restrict__ eci,
    const float* __restrict__ kcr, const float* __restrict__ kci,
    const float* __restrict__ ear, const float* __restrict__ eai,
    const float* __restrict__ kar, const float* __restrict__ kai,
    float* __restrict__ out, int W)
{
    int t = blockIdx.x * blockDim.x + threadIdx.x;
    int w = t >> 4;      // one 16-lane group per wavelength
    int j = t & 15;      // lane-in-group: owns layers 4j..4j+3
    if (w >= W) return;

    float lo = mindp[0], hi = maxdp[0];
    float k0 = 6.2831852f / (wl[w] * 1e-6f);

    // thickness for my 4 layers
    float4 tp4 = *reinterpret_cast<const float4*>(thickP + 4 * j);
    float k0d[4];
    {
        const float* tpv = reinterpret_cast<const float*>(&tp4);
        #pragma unroll
        for (int q = 0; q < 4; q++) {
            float sg = 1.0f / (1.0f + expf(-tpv[q]));
            float d  = fmaf(sg, (hi - lo), lo) * 1e-9f;
            k0d[q] = k0 * d;
        }
    }

    size_t base = (size_t)w * LTOT + 4 * j;
    float4 v_ecr = *reinterpret_cast<const float4*>(ecr + base);
    float4 v_eci = *reinterpret_cast<const float4*>(eci + base);
    float4 v_kcr = *reinterpret_cast<const float4*>(kcr + base);
    float4 v_kci = *reinterpret_cast<const float4*>(kci + base);
    float4 v_ear = *reinterpret_cast<const float4*>(ear + base);
    float4 v_eai = *reinterpret_cast<const float4*>(eai + base);
    float4 v_kar = *reinterpret_cast<const float4*>(kar + base);
    float4 v_kai = *reinterpret_cast<const float4*>(kai + base);
    const float* pecr = reinterpret_cast<const float*>(&v_ecr);
    const float* peci = reinterpret_cast<const float*>(&v_eci);
    const float* pkcr = reinterpret_cast<const float*>(&v_kcr);
    const float* pkci = reinterpret_cast<const float*>(&v_kci);
    const float* pear = reinterpret_cast<const float*>(&v_ear);
    const float* peai = reinterpret_cast<const float*>(&v_eai);
    const float* pkar = reinterpret_cast<const float*>(&v_kar);
    const float* pkai = reinterpret_cast<const float*>(&v_kai);

    // chains: 0: stack c, sigma=+1 (A_r)   1: stack c, sigma=-1 (A_l)
    //         2: stack a, sigma=+1         3: stack a, sigma=-1
    Mat P[4];
    #pragma unroll
    for (int q = 0; q < 4; q++) {
        cpx ec = { pecr[q], peci[q] };
        cpx kc = { pkcr[q], pkci[q] };
        cpx ea = { pear[q], peai[q] };
        cpx ka = { pkar[q], pkai[q] };
        cpx n0c = csqrt_pos(ec);
        cpx n0a = csqrt_pos(ea);
        float invc = 1.0f / fmaf(n0c.r, n0c.r, n0c.i * n0c.i);
        float inva = 1.0f / fmaf(n0a.r, n0a.r, n0a.i * n0a.i);
        bool first = (q == 0);
        accum(P[0], first, k0d[q], n0c, invc, kc, +1.0f);
        accum(P[1], first, k0d[q], n0c, invc, kc, -1.0f);
        accum(P[2], first, k0d[q], n0a, inva, ka, +1.0f);
        accum(P[3], first, k0d[q], n0a, inva, ka, -1.0f);
    }

    // ordered butterfly reduction across 16 lanes: left operand = lower lane index
    #pragma unroll
    for (int m = 1; m < 16; m <<= 1) {
        bool up = (j & m) != 0;
        #pragma unroll
        for (int ch = 0; ch < 4; ch++) {
            Mat O = shfl_mat(P[ch], m);
            Mat Lf, Rt;
            Lf.e00 = up ? O.e00 : P[ch].e00; Lf.e01 = up ? O.e01 : P[ch].e01;
            Lf.e10 = up ? O.e10 : P[ch].e10; Lf.e11 = up ? O.e11 : P[ch].e11;
            Rt.e00 = up ? P[ch].e00 : O.e00; Rt.e01 = up ? P[ch].e01 : O.e01;
            Rt.e10 = up ? P[ch].e10 : O.e10; Rt.e11 = up ? P[ch].e11 : O.e11;
            P[ch] = mmul(Lf, Rt);
        }
    }

    // absorbance per chain (redundant across the 16 lanes; lane 0 writes)
    float A[4];
    #pragma unroll
    for (int ch = 0; ch < 4; ch++) {
        float dr = P[ch].e00.r + 1.45f * P[ch].e01.r + P[ch].e10.r + 1.45f * P[ch].e11.r;
        float di = P[ch].e00.i + 1.45f * P[ch].e01.i + P[ch].e10.i + 1.45f * P[ch].e11.i;
        float den = fmaf(dr, dr, di * di);
        float T = 5.8f / den;              // N_OUT * |2/denom|^2
        A[ch] = -log10f(T + 1e-12f);
    }

    if (j == 0) {
        const float SC = (2.0f * 0.87f - 1.0f) * 32980.0f;
        out[0 * W + w] = (A[1] - A[0]) * SC;   // cd_c * scale
        out[1 * W + w] = (A[3] - A[2]) * SC;   // cd_a * scale
        out[2 * W + w] = 0.5f * (A[1] + A[0]); // abs_c
        out[3 * W + w] = 0.5f * (A[3] + A[2]); // abs_a
    }
}

extern "C" void kernel_launch(void* const* d_in, const int* in_sizes, int n_in,
                              void* d_out, int out_size, void* d_ws, size_t ws_size,
                              hipStream_t stream) {
    const float* wl     = (const float*)d_in[0];
    const float* thickP = (const float*)d_in[1];
    const float* mind   = (const float*)d_in[2];
    const float* maxd   = (const float*)d_in[3];
    const float* ecr    = (const float*)d_in[4];
    const float* eci    = (const float*)d_in[5];
    const float* kcr    = (const float*)d_in[6];
    const float* kci    = (const float*)d_in[7];
    const float* ear    = (const float*)d_in[8];
    const float* eai    = (const float*)d_in[9];
    const float* kar    = (const float*)d_in[10];
    const float* kai    = (const float*)d_in[11];
    float* out = (float*)d_out;

    int W = in_sizes[0];
    int threads = W * 16;
    int block = 256;
    int grid = (threads + block - 1) / block;
    chiral_kernel<<<grid, block, 0, stream>>>(wl, thickP, mind, maxd,
                                              ecr, eci, kcr, kci,
                                              ear, eai, kar, kai, out, W);
}

// Round 2
// 188.359 us; speedup vs baseline: 1.1522x; 1.1522x over previous
//
#include <hip/hip_runtime.h>
#include <math.h>

#define LTOT 64
#define GL   4            // lanes per wavelength
#define LPL  (LTOT / GL)  // 16 layers per lane

#define INV2PI  0.15915494309189535f
#define LOG2E   1.4426950408889634f
#define LOG10_2 0.30102999566398120f

struct cpx { float r, i; };
struct Mat { cpx e00, e01, e10, e11; };

__device__ __forceinline__ cpx cmul(cpx a, cpx b) {
    return { fmaf(a.r, b.r, -a.i * b.i), fmaf(a.r, b.i, a.i * b.r) };
}
__device__ __forceinline__ cpx cmadd(cpx a, cpx b, cpx c) {   // a*b + c
    return { fmaf(a.r, b.r, fmaf(-a.i, b.i, c.r)),
             fmaf(a.r, b.i, fmaf( a.i, b.r, c.i)) };
}
__device__ __forceinline__ Mat mmul(const Mat& A, const Mat& B) {
    Mat C;
    C.e00 = cmadd(A.e01, B.e10, cmul(A.e00, B.e00));
    C.e01 = cmadd(A.e01, B.e11, cmul(A.e00, B.e01));
    C.e10 = cmadd(A.e11, B.e10, cmul(A.e10, B.e00));
    C.e11 = cmadd(A.e11, B.e11, cmul(A.e10, B.e01));
    return C;
}
// principal sqrt; valid for re>0, im>=0 (eps_re in [1.8,4.5])
__device__ __forceinline__ cpx csqrt_pos(cpx z) {
    float m  = __builtin_amdgcn_sqrtf(fmaf(z.r, z.r, z.i * z.i));
    float re = __builtin_amdgcn_sqrtf(0.5f * (m + z.r));
    float im = 0.5f * z.i * __builtin_amdgcn_rcpf(re);
    return { re, im };
}

// one layer, one sigma: build M and P = P @ M (or P = M if first).
// xrev = Re(delta)/2pi ; y = Im(delta) (|y| <= ~0.17 -> poly cosh/sinh)
__device__ __forceinline__ void accum(Mat& P, bool first, float xrev, float y,
                                      cpx n0, float inv_n0sq) {
    float rf = __builtin_amdgcn_fractf(xrev);
    float s_ = __builtin_amdgcn_sinf(rf);
    float c_ = __builtin_amdgcn_cosf(rf);
    float y2 = y * y;
    float chv = fmaf(y2, fmaf(y2, 0.0416666667f, 0.5f), 1.0f);          // cosh
    float shv = y * fmaf(y2, fmaf(y2, 0.0083333333f, 0.1666666667f), 1.0f); // sinh
    cpx cc = { c_ * chv, -s_ * shv };          // cos(delta)
    cpx ss = { s_ * chv,  c_ * shv };          // sin(delta)
    // q = s / Y  (Y = n0)
    cpx qq = { (ss.r * n0.r + ss.i * n0.i) * inv_n0sq,
               (ss.i * n0.r - ss.r * n0.i) * inv_n0sq };
    cpx m01 = { -qq.i, qq.r };                 // i * s / Y
    cpx p   = cmul(n0, ss);
    cpx m10 = { -p.i, p.r };                   // i * Y * s
    if (first) {
        P.e00 = cc; P.e01 = m01; P.e10 = m10; P.e11 = cc;
    } else {
        Mat C;
        C.e00 = cmadd(P.e01, m10, cmul(P.e00, cc));
        C.e01 = cmadd(P.e01, cc,  cmul(P.e00, m01));
        C.e10 = cmadd(P.e11, m10, cmul(P.e10, cc));
        C.e11 = cmadd(P.e11, cc,  cmul(P.e10, m01));
        P = C;
    }
}

__device__ __forceinline__ Mat shfl_mat(const Mat& M, int mask) {
    Mat R;
    R.e00.r = __shfl_xor(M.e00.r, mask); R.e00.i = __shfl_xor(M.e00.i, mask);
    R.e01.r = __shfl_xor(M.e01.r, mask); R.e01.i = __shfl_xor(M.e01.i, mask);
    R.e10.r = __shfl_xor(M.e10.r, mask); R.e10.i = __shfl_xor(M.e10.i, mask);
    R.e11.r = __shfl_xor(M.e11.r, mask); R.e11.i = __shfl_xor(M.e11.i, mask);
    return R;
}

__global__ __launch_bounds__(256) void chiral_kernel(
    const float* __restrict__ wl,  const float* __restrict__ thickP,
    const float* __restrict__ mindp, const float* __restrict__ maxdp,
    const float* __restrict__ ecr, const float* __restrict__ eci,
    const float* __restrict__ kcr, const float* __restrict__ kci,
    const float* __restrict__ ear, const float* __restrict__ eai,
    const float* __restrict__ kar, const float* __restrict__ kai,
    float* __restrict__ out, int W)
{
    int t = blockIdx.x * blockDim.x + threadIdx.x;
    int w = t >> 2;      // one 4-lane group per wavelength
    int j = t & 3;       // lane-in-group: owns layers 16j..16j+15
    if (w >= W) return;

    float lo = mindp[0], hi = maxdp[0];
    float k0 = 6.2831852e6f * __builtin_amdgcn_rcpf(wl[w]);

    // chains: 0: stack c, sigma=+1 (A_r)   1: stack c, sigma=-1 (A_l)
    //         2: stack a, sigma=+1         3: stack a, sigma=-1
    Mat P[4];

    size_t rowbase = (size_t)w * LTOT + (size_t)(LPL * j);

    #pragma unroll
    for (int q4 = 0; q4 < 4; q4++) {
        size_t base = rowbase + 4 * q4;
        float4 tp4   = *reinterpret_cast<const float4*>(thickP + LPL * j + 4 * q4);
        float4 v_ecr = *reinterpret_cast<const float4*>(ecr + base);
        float4 v_eci = *reinterpret_cast<const float4*>(eci + base);
        float4 v_kcr = *reinterpret_cast<const float4*>(kcr + base);
        float4 v_kci = *reinterpret_cast<const float4*>(kci + base);
        float4 v_ear = *reinterpret_cast<const float4*>(ear + base);
        float4 v_eai = *reinterpret_cast<const float4*>(eai + base);
        float4 v_kar = *reinterpret_cast<const float4*>(kar + base);
        float4 v_kai = *reinterpret_cast<const float4*>(kai + base);
        const float* ptp  = reinterpret_cast<const float*>(&tp4);
        const float* pecr = reinterpret_cast<const float*>(&v_ecr);
        const float* peci = reinterpret_cast<const float*>(&v_eci);
        const float* pkcr = reinterpret_cast<const float*>(&v_kcr);
        const float* pkci = reinterpret_cast<const float*>(&v_kci);
        const float* pear = reinterpret_cast<const float*>(&v_ear);
        const float* peai = reinterpret_cast<const float*>(&v_eai);
        const float* pkar = reinterpret_cast<const float*>(&v_kar);
        const float* pkai = reinterpret_cast<const float*>(&v_kai);

        #pragma unroll
        for (int q = 0; q < 4; q++) {
            bool first = (q4 == 0 && q == 0);
            // sigmoid -> thickness -> k0*d
            float tr = ptp[q];
            float sg = __builtin_amdgcn_rcpf(1.0f + __builtin_amdgcn_exp2f(-tr * LOG2E));
            float d  = fmaf(sg, (hi - lo), lo) * 1e-9f;
            float kd = k0 * d;

            // stack c
            {
                cpx e  = { pecr[q], peci[q] };
                cpx kp = { pkcr[q], pkci[q] };
                cpx n0 = csqrt_pos(e);
                float inv = __builtin_amdgcn_rcpf(fmaf(n0.r, n0.r, n0.i * n0.i));
                float ar = kd * n0.r, ai = kd * n0.i;
                float br = kd * kp.r, bi = kd * kp.i;
                accum(P[0], first, (ar + br) * INV2PI, ai + bi, n0, inv);
                accum(P[1], first, (ar - br) * INV2PI, ai - bi, n0, inv);
            }
            // stack a
            {
                cpx e  = { pear[q], peai[q] };
                cpx kp = { pkar[q], pkai[q] };
                cpx n0 = csqrt_pos(e);
                float inv = __builtin_amdgcn_rcpf(fmaf(n0.r, n0.r, n0.i * n0.i));
                float ar = kd * n0.r, ai = kd * n0.i;
                float br = kd * kp.r, bi = kd * kp.i;
                accum(P[2], first, (ar + br) * INV2PI, ai + bi, n0, inv);
                accum(P[3], first, (ar - br) * INV2PI, ai - bi, n0, inv);
            }
        }
    }

    // ordered butterfly across the 4 lanes: left operand = lower lane index
    #pragma unroll
    for (int m = 1; m < GL; m <<= 1) {
        bool up = (j & m) != 0;
        #pragma unroll
        for (int ch = 0; ch < 4; ch++) {
            Mat O = shfl_mat(P[ch], m);
            Mat Lf, Rt;
            Lf.e00 = up ? O.e00 : P[ch].e00; Lf.e01 = up ? O.e01 : P[ch].e01;
            Lf.e10 = up ? O.e10 : P[ch].e10; Lf.e11 = up ? O.e11 : P[ch].e11;
            Rt.e00 = up ? P[ch].e00 : O.e00; Rt.e01 = up ? P[ch].e01 : O.e01;
            Rt.e10 = up ? P[ch].e10 : O.e10; Rt.e11 = up ? P[ch].e11 : O.e11;
            P[ch] = mmul(Lf, Rt);
        }
    }

    if (j == 0) {
        float A[4];
        #pragma unroll
        for (int ch = 0; ch < 4; ch++) {
            float dr = P[ch].e00.r + 1.45f * P[ch].e01.r + P[ch].e10.r + 1.45f * P[ch].e11.r;
            float di = P[ch].e00.i + 1.45f * P[ch].e01.i + P[ch].e10.i + 1.45f * P[ch].e11.i;
            float den = fmaf(dr, dr, di * di);
            float T = 5.8f * __builtin_amdgcn_rcpf(den);   // N_OUT * |2/denom|^2
            A[ch] = -__builtin_amdgcn_logf(T + 1e-12f) * LOG10_2;
        }
        const float SC = (2.0f * 0.87f - 1.0f) * 32980.0f;
        out[0 * W + w] = (A[1] - A[0]) * SC;   // cd_c * scale
        out[1 * W + w] = (A[3] - A[2]) * SC;   // cd_a * scale
        out[2 * W + w] = 0.5f * (A[1] + A[0]); // abs_c
        out[3 * W + w] = 0.5f * (A[3] + A[2]); // abs_a
    }
}

extern "C" void kernel_launch(void* const* d_in, const int* in_sizes, int n_in,
                              void* d_out, int out_size, void* d_ws, size_t ws_size,
                              hipStream_t stream) {
    const float* wl     = (const float*)d_in[0];
    const float* thickP = (const float*)d_in[1];
    const float* mind   = (const float*)d_in[2];
    const float* maxd   = (const float*)d_in[3];
    const float* ecr    = (const float*)d_in[4];
    const float* eci    = (const float*)d_in[5];
    const float* kcr    = (const float*)d_in[6];
    const float* kci    = (const float*)d_in[7];
    const float* ear    = (const float*)d_in[8];
    const float* eai    = (const float*)d_in[9];
    const float* kar    = (const float*)d_in[10];
    const float* kai    = (const float*)d_in[11];
    float* out = (float*)d_out;

    int W = in_sizes[0];
    int threads = W * GL;
    int block = 256;
    int grid = (threads + block - 1) / block;
    chiral_kernel<<<grid, block, 0, stream>>>(wl, thickP, mind, maxd,
                                              ecr, eci, kcr, kci,
                                              ear, eai, kar, kai, out, W);
}

// Round 3
// 180.077 us; speedup vs baseline: 1.2052x; 1.0460x over previous
//
#include <hip/hip_runtime.h>
#include <math.h>

#define LTOT 64
#define GL   8            // lanes per wavelength
#define LPL  (LTOT / GL)  // 8 layers per lane

#define INV2PI  0.15915494309189535f
#define LOG2E   1.4426950408889634f
#define LOG10_2 0.30102999566398120f

struct cpx { float r, i; };
struct Mat { cpx e00, e01, e10, e11; };

__device__ __forceinline__ cpx cmul(cpx a, cpx b) {
    return { fmaf(a.r, b.r, -a.i * b.i), fmaf(a.r, b.i, a.i * b.r) };
}
__device__ __forceinline__ cpx cmadd(cpx a, cpx b, cpx c) {   // a*b + c
    return { fmaf(a.r, b.r, fmaf(-a.i, b.i, c.r)),
             fmaf(a.r, b.i, fmaf( a.i, b.r, c.i)) };
}
__device__ __forceinline__ Mat mmul(const Mat& A, const Mat& B) {
    Mat C;
    C.e00 = cmadd(A.e01, B.e10, cmul(A.e00, B.e00));
    C.e01 = cmadd(A.e01, B.e11, cmul(A.e00, B.e01));
    C.e10 = cmadd(A.e11, B.e10, cmul(A.e10, B.e00));
    C.e11 = cmadd(A.e11, B.e11, cmul(A.e10, B.e01));
    return C;
}
// n0 = sqrt(eps) (principal, re>0,im>=0) and inv = 1/|n0|^2 = 1/|eps|
__device__ __forceinline__ void csqrt_inv(cpx z, cpx& n0, float& inv) {
    float m = __builtin_amdgcn_sqrtf(fmaf(z.r, z.r, z.i * z.i)); // |eps|
    float x = 0.5f * (m + z.r);
    float t = __builtin_amdgcn_rsqf(x);
    n0.r = x * t;                 // sqrt(x)
    n0.i = 0.5f * z.i * t;
    inv  = __builtin_amdgcn_rcpf(m);
}

// one layer, one sigma: P = P @ M (or P = M if first).
// xrev = Re(delta)/2pi ; y = Im(delta) (|y| <= ~0.17 -> poly cosh/sinh)
__device__ __forceinline__ void accum(Mat& P, bool first, float xrev, float y,
                                      cpx n0, float inv_n0sq) {
    float rf = __builtin_amdgcn_fractf(xrev);
    float s_ = __builtin_amdgcn_sinf(rf);
    float c_ = __builtin_amdgcn_cosf(rf);
    float y2 = y * y;
    float chv = fmaf(y2, fmaf(y2, 0.0416666667f, 0.5f), 1.0f);              // cosh
    float shv = y * fmaf(y2, fmaf(y2, 0.0083333333f, 0.1666666667f), 1.0f); // sinh
    cpx cc = { c_ * chv, -s_ * shv };          // cos(delta)
    cpx ss = { s_ * chv,  c_ * shv };          // sin(delta)
    cpx qq = { (ss.r * n0.r + ss.i * n0.i) * inv_n0sq,
               (ss.i * n0.r - ss.r * n0.i) * inv_n0sq };
    cpx m01 = { -qq.i, qq.r };                 // i * s / Y
    cpx p   = cmul(n0, ss);
    cpx m10 = { -p.i, p.r };                   // i * Y * s
    if (first) {
        P.e00 = cc; P.e01 = m01; P.e10 = m10; P.e11 = cc;
    } else {
        Mat C;
        C.e00 = cmadd(P.e01, m10, cmul(P.e00, cc));
        C.e01 = cmadd(P.e01, cc,  cmul(P.e00, m01));
        C.e10 = cmadd(P.e11, m10, cmul(P.e10, cc));
        C.e11 = cmadd(P.e11, cc,  cmul(P.e10, m01));
        P = C;
    }
}

__device__ __forceinline__ Mat shfl_mat(const Mat& M, int mask) {
    Mat R;
    R.e00.r = __shfl_xor(M.e00.r, mask); R.e00.i = __shfl_xor(M.e00.i, mask);
    R.e01.r = __shfl_xor(M.e01.r, mask); R.e01.i = __shfl_xor(M.e01.i, mask);
    R.e10.r = __shfl_xor(M.e10.r, mask); R.e10.i = __shfl_xor(M.e10.i, mask);
    R.e11.r = __shfl_xor(M.e11.r, mask); R.e11.i = __shfl_xor(M.e11.i, mask);
    return R;
}

__global__ __launch_bounds__(256, 4) void chiral_kernel(
    const float* __restrict__ wl,  const float* __restrict__ thickP,
    const float* __restrict__ mindp, const float* __restrict__ maxdp,
    const float* __restrict__ ecr, const float* __restrict__ eci,
    const float* __restrict__ kcr, const float* __restrict__ kci,
    const float* __restrict__ ear, const float* __restrict__ eai,
    const float* __restrict__ kar, const float* __restrict__ kai,
    float* __restrict__ out, int W)
{
    int t = blockIdx.x * blockDim.x + threadIdx.x;
    int w = t >> 3;      // one 8-lane group per wavelength
    int j = t & 7;       // lane-in-group: owns layers 8j..8j+7
    if (w >= W) return;

    size_t rowbase = (size_t)w * LTOT + (size_t)(LPL * j);

    // ---- prefetch everything (16 float4 of per-(w,layer) data + thickP) ----
    float4 Ltp[2], Lecr[2], Leci[2], Lkcr[2], Lkci[2], Lear[2], Leai[2], Lkar[2], Lkai[2];
    #pragma unroll
    for (int h = 0; h < 2; h++) {
        size_t b = rowbase + 4 * h;
        Ltp[h]  = *reinterpret_cast<const float4*>(thickP + LPL * j + 4 * h);
        Lecr[h] = *reinterpret_cast<const float4*>(ecr + b);
        Leci[h] = *reinterpret_cast<const float4*>(eci + b);
        Lkcr[h] = *reinterpret_cast<const float4*>(kcr + b);
        Lkci[h] = *reinterpret_cast<const float4*>(kci + b);
        Lear[h] = *reinterpret_cast<const float4*>(ear + b);
        Leai[h] = *reinterpret_cast<const float4*>(eai + b);
        Lkar[h] = *reinterpret_cast<const float4*>(kar + b);
        Lkai[h] = *reinterpret_cast<const float4*>(kai + b);
    }

    float lo = mindp[0], hi = maxdp[0];
    float k0 = 6.2831852e6f * __builtin_amdgcn_rcpf(wl[w]);

    // chains: 0: c,+1 (A_r)  1: c,-1 (A_l)  2: a,+1  3: a,-1
    Mat P[4];

    #pragma unroll
    for (int h = 0; h < 2; h++) {
        const float* ptp  = reinterpret_cast<const float*>(&Ltp[h]);
        const float* pecr = reinterpret_cast<const float*>(&Lecr[h]);
        const float* peci = reinterpret_cast<const float*>(&Leci[h]);
        const float* pkcr = reinterpret_cast<const float*>(&Lkcr[h]);
        const float* pkci = reinterpret_cast<const float*>(&Lkci[h]);
        const float* pear = reinterpret_cast<const float*>(&Lear[h]);
        const float* peai = reinterpret_cast<const float*>(&Leai[h]);
        const float* pkar = reinterpret_cast<const float*>(&Lkar[h]);
        const float* pkai = reinterpret_cast<const float*>(&Lkai[h]);

        #pragma unroll
        for (int q = 0; q < 4; q++) {
            bool first = (h == 0 && q == 0);
            float tr = ptp[q];
            float sg = __builtin_amdgcn_rcpf(1.0f + __builtin_amdgcn_exp2f(-tr * LOG2E));
            float d  = fmaf(sg, (hi - lo), lo) * 1e-9f;
            float kd = k0 * d;

            {   // stack c
                cpx e  = { pecr[q], peci[q] };
                cpx kp = { pkcr[q], pkci[q] };
                cpx n0; float inv;
                csqrt_inv(e, n0, inv);
                float ar = kd * n0.r, ai = kd * n0.i;
                float br = kd * kp.r, bi = kd * kp.i;
                accum(P[0], first, (ar + br) * INV2PI, ai + bi, n0, inv);
                accum(P[1], first, (ar - br) * INV2PI, ai - bi, n0, inv);
            }
            {   // stack a
                cpx e  = { pear[q], peai[q] };
                cpx kp = { pkar[q], pkai[q] };
                cpx n0; float inv;
                csqrt_inv(e, n0, inv);
                float ar = kd * n0.r, ai = kd * n0.i;
                float br = kd * kp.r, bi = kd * kp.i;
                accum(P[2], first, (ar + br) * INV2PI, ai + bi, n0, inv);
                accum(P[3], first, (ar - br) * INV2PI, ai - bi, n0, inv);
            }
        }
    }

    // ordered butterfly across the 8 lanes: left operand = lower lane index
    #pragma unroll
    for (int m = 1; m < GL; m <<= 1) {
        bool up = (j & m) != 0;
        #pragma unroll
        for (int ch = 0; ch < 4; ch++) {
            Mat O = shfl_mat(P[ch], m);
            Mat Lf, Rt;
            Lf.e00 = up ? O.e00 : P[ch].e00; Lf.e01 = up ? O.e01 : P[ch].e01;
            Lf.e10 = up ? O.e10 : P[ch].e10; Lf.e11 = up ? O.e11 : P[ch].e11;
            Rt.e00 = up ? P[ch].e00 : O.e00; Rt.e01 = up ? P[ch].e01 : O.e01;
            Rt.e10 = up ? P[ch].e10 : O.e10; Rt.e11 = up ? P[ch].e11 : O.e11;
            P[ch] = mmul(Lf, Rt);
        }
    }

    if (j == 0) {
        float A[4];
        #pragma unroll
        for (int ch = 0; ch < 4; ch++) {
            float dr = P[ch].e00.r + 1.45f * P[ch].e01.r + P[ch].e10.r + 1.45f * P[ch].e11.r;
            float di = P[ch].e00.i + 1.45f * P[ch].e01.i + P[ch].e10.i + 1.45f * P[ch].e11.i;
            float den = fmaf(dr, dr, di * di);
            float T = 5.8f * __builtin_amdgcn_rcpf(den);   // N_OUT * |2/denom|^2
            A[ch] = -__builtin_amdgcn_logf(T + 1e-12f) * LOG10_2;
        }
        const float SC = (2.0f * 0.87f - 1.0f) * 32980.0f;
        out[0 * W + w] = (A[1] - A[0]) * SC;   // cd_c * scale
        out[1 * W + w] = (A[3] - A[2]) * SC;   // cd_a * scale
        out[2 * W + w] = 0.5f * (A[1] + A[0]); // abs_c
        out[3 * W + w] = 0.5f * (A[3] + A[2]); // abs_a
    }
}

extern "C" void kernel_launch(void* const* d_in, const int* in_sizes, int n_in,
                              void* d_out, int out_size, void* d_ws, size_t ws_size,
                              hipStream_t stream) {
    const float* wl     = (const float*)d_in[0];
    const float* thickP = (const float*)d_in[1];
    const float* mind   = (const float*)d_in[2];
    const float* maxd   = (const float*)d_in[3];
    const float* ecr    = (const float*)d_in[4];
    const float* eci    = (const float*)d_in[5];
    const float* kcr    = (const float*)d_in[6];
    const float* kci    = (const float*)d_in[7];
    const float* ear    = (const float*)d_in[8];
    const float* eai    = (const float*)d_in[9];
    const float* kar    = (const float*)d_in[10];
    const float* kai    = (const float*)d_in[11];
    float* out = (float*)d_out;

    int W = in_sizes[0];
    int threads = W * GL;
    int block = 256;
    int grid = (threads + block - 1) / block;
    chiral_kernel<<<grid, block, 0, stream>>>(wl, thickP, mind, maxd,
                                              ecr, eci, kcr, kci,
                                              ear, eai, kar, kai, out, W);
}

// Round 4
// 174.085 us; speedup vs baseline: 1.2467x; 1.0344x over previous
//
#include <hip/hip_runtime.h>
#include <math.h>

typedef float f32x2 __attribute__((ext_vector_type(2)));

#define LTOT 64
#define GL   8            // lanes per wavelength
#define LPL  8            // layers per lane

#define INV2PI  0.15915494309189535f
#define LOG2E   1.4426950408889634f
#define LOG10_2 0.30102999566398120f

// complex value for a packed pair of chains: lo = sigma=+1, hi = sigma=-1
struct C2 { f32x2 r, i; };
// transfer matrix in factored form [[A, iB],[iC, D]]
struct M2 { C2 A, B, C, D; };

__device__ __forceinline__ f32x2 shx(f32x2 v, int m) {
    f32x2 r;
    r.x = __shfl_xor(v.x, m);
    r.y = __shfl_xor(v.y, m);
    return r;
}

// one layer for one stack, both sigmas packed: P = P @ M_layer (or P = M if first)
__device__ __forceinline__ void layer_stack(M2& M, bool first, float kd,
                                            float er, float ei, float kr, float ki) {
    // n0 = sqrt(eps) (principal, er>0, ei>=0), inv = 1/|n0|^2 = 1/|eps|
    float mm  = __builtin_amdgcn_sqrtf(fmaf(er, er, ei * ei));
    float x   = 0.5f * (mm + er);
    float rx  = __builtin_amdgcn_rsqf(x);
    float n0r = x * rx;
    float n0i = 0.5f * ei * rx;
    float inv = __builtin_amdgcn_rcpf(mm);

    float ar = kd * n0r, ai = kd * n0i;   // a = kd * n0
    float br = kd * kr,  bi = kd * ki;    // b = kd * kappa (|br| <= ~0.024)

    // trig of a_r (native, revolutions); small-angle polys for b_r
    float rf = __builtin_amdgcn_fractf(ar * INV2PI);
    float sa = __builtin_amdgcn_sinf(rf);
    float ca = __builtin_amdgcn_cosf(rf);
    float b2 = br * br;
    float sb = br * fmaf(b2, -0.16666667f, 1.0f);
    float cb = fmaf(b2, -0.5f, 1.0f);
    float u = sa * cb, v = ca * sb, wq = ca * cb, zq = sa * sb;

    f32x2 S, Cx, Y;
    S.x = u + v;   S.y = u - v;     // sin(ar +/- br)
    Cx.x = wq - zq; Cx.y = wq + zq; // cos(ar +/- br)
    Y.x = ai + bi; Y.y = ai - bi;   // Im(delta), |Y| <= ~0.17

    // cosh/sinh by poly (err < 3e-8 on this range)
    f32x2 y2 = Y * Y;
    f32x2 ch = (y2 * 0.041666667f + 0.5f) * y2 + 1.0f;
    f32x2 sh = Y * ((y2 * 0.0083333333f + 0.16666667f) * y2 + 1.0f);

    // cos(delta) = (Cx*ch, -S*sh) ; sin(delta) = (S*ch, Cx*sh)
    f32x2 c_r = Cx * ch;
    f32x2 c_i = -(S * sh);
    f32x2 s_r = S * ch;
    f32x2 s_i = Cx * sh;

    // q = s * conj(n0) * inv  (so m01 = i q) ; p = n0 * s (so m10 = i p)
    f32x2 q_r = (s_r * n0r + s_i * n0i) * inv;
    f32x2 q_i = (s_i * n0r - s_r * n0i) * inv;
    f32x2 p_r = s_r * n0r - s_i * n0i;
    f32x2 p_i = s_i * n0r + s_r * n0i;

    if (first) {
        M.A.r = c_r; M.A.i = c_i;
        M.B.r = q_r; M.B.i = q_i;
        M.C.r = p_r; M.C.i = p_i;
        M.D.r = c_r; M.D.i = c_i;
    } else {
        // A' = A c - B p ; B' = A q + B c ; C' = C c + D p ; D' = D c - C q
        f32x2 nAr = M.A.r*c_r - M.A.i*c_i - M.B.r*p_r + M.B.i*p_i;
        f32x2 nAi = M.A.r*c_i + M.A.i*c_r - M.B.r*p_i - M.B.i*p_r;
        f32x2 nBr = M.A.r*q_r - M.A.i*q_i + M.B.r*c_r - M.B.i*c_i;
        f32x2 nBi = M.A.r*q_i + M.A.i*q_r + M.B.r*c_i + M.B.i*c_r;
        f32x2 nCr = M.C.r*c_r - M.C.i*c_i + M.D.r*p_r - M.D.i*p_i;
        f32x2 nCi = M.C.r*c_i + M.C.i*c_r + M.D.r*p_i + M.D.i*p_r;
        f32x2 nDr = M.D.r*c_r - M.D.i*c_i - M.C.r*q_r + M.C.i*q_i;
        f32x2 nDi = M.D.r*c_i + M.D.i*c_r - M.C.r*q_i - M.C.i*q_r;
        M.A.r = nAr; M.A.i = nAi; M.B.r = nBr; M.B.i = nBi;
        M.C.r = nCr; M.C.i = nCi; M.D.r = nDr; M.D.i = nDi;
    }
}

// L = L · R in factored form:
// A = Al Ar - Bl Cr ; B = Al Br + Bl Dr ; C = Cl Ar + Dl Cr ; D = Dl Dr - Cl Br
__device__ __forceinline__ void combine(M2& L, const M2& R) {
    f32x2 nAr = L.A.r*R.A.r - L.A.i*R.A.i - L.B.r*R.C.r + L.B.i*R.C.i;
    f32x2 nAi = L.A.r*R.A.i + L.A.i*R.A.r - L.B.r*R.C.i - L.B.i*R.C.r;
    f32x2 nBr = L.A.r*R.B.r - L.A.i*R.B.i + L.B.r*R.D.r - L.B.i*R.D.i;
    f32x2 nBi = L.A.r*R.B.i + L.A.i*R.B.r + L.B.r*R.D.i + L.B.i*R.D.r;
    f32x2 nCr = L.C.r*R.A.r - L.C.i*R.A.i + L.D.r*R.C.r - L.D.i*R.C.i;
    f32x2 nCi = L.C.r*R.A.i + L.C.i*R.A.r + L.D.r*R.C.i + L.D.i*R.C.r;
    f32x2 nDr = L.D.r*R.D.r - L.D.i*R.D.i - L.C.r*R.B.r + L.C.i*R.B.i;
    f32x2 nDi = L.D.r*R.D.i + L.D.i*R.D.r - L.C.r*R.B.i - L.C.i*R.B.r;
    L.A.r = nAr; L.A.i = nAi; L.B.r = nBr; L.B.i = nBi;
    L.C.r = nCr; L.C.i = nCi; L.D.r = nDr; L.D.i = nDi;
}

__device__ __forceinline__ M2 shfl_m2(const M2& M, int m) {
    M2 R;
    R.A.r = shx(M.A.r, m); R.A.i = shx(M.A.i, m);
    R.B.r = shx(M.B.r, m); R.B.i = shx(M.B.i, m);
    R.C.r = shx(M.C.r, m); R.C.i = shx(M.C.i, m);
    R.D.r = shx(M.D.r, m); R.D.i = shx(M.D.i, m);
    return R;
}

__global__ __launch_bounds__(256, 4) void chiral_kernel(
    const float* __restrict__ wl,  const float* __restrict__ thickP,
    const float* __restrict__ mindp, const float* __restrict__ maxdp,
    const float* __restrict__ ecr, const float* __restrict__ eci,
    const float* __restrict__ kcr, const float* __restrict__ kci,
    const float* __restrict__ ear, const float* __restrict__ eai,
    const float* __restrict__ kar, const float* __restrict__ kai,
    float* __restrict__ out, int W)
{
    int t = blockIdx.x * blockDim.x + threadIdx.x;
    int w = t >> 3;      // one 8-lane group per wavelength
    int j = t & 7;       // lane owns layers 8j..8j+7
    if (w >= W) return;

    size_t rowbase = (size_t)w * LTOT + (size_t)(LPL * j);

    float4 Ltp[2], Lecr[2], Leci[2], Lkcr[2], Lkci[2], Lear[2], Leai[2], Lkar[2], Lkai[2];
    #pragma unroll
    for (int h = 0; h < 2; h++) {
        size_t b = rowbase + 4 * h;
        Ltp[h]  = *reinterpret_cast<const float4*>(thickP + LPL * j + 4 * h);
        Lecr[h] = *reinterpret_cast<const float4*>(ecr + b);
        Leci[h] = *reinterpret_cast<const float4*>(eci + b);
        Lkcr[h] = *reinterpret_cast<const float4*>(kcr + b);
        Lkci[h] = *reinterpret_cast<const float4*>(kci + b);
        Lear[h] = *reinterpret_cast<const float4*>(ear + b);
        Leai[h] = *reinterpret_cast<const float4*>(eai + b);
        Lkar[h] = *reinterpret_cast<const float4*>(kar + b);
        Lkai[h] = *reinterpret_cast<const float4*>(kai + b);
    }

    float lo = mindp[0], hi = maxdp[0];
    float k0 = 6.2831852e6f * __builtin_amdgcn_rcpf(wl[w]);

    M2 Mc, Ma;   // stack c, stack a (each holds sigma +/- packed)

    #pragma unroll
    for (int h = 0; h < 2; h++) {
        const float* ptp  = reinterpret_cast<const float*>(&Ltp[h]);
        const float* pecr = reinterpret_cast<const float*>(&Lecr[h]);
        const float* peci = reinterpret_cast<const float*>(&Leci[h]);
        const float* pkcr = reinterpret_cast<const float*>(&Lkcr[h]);
        const float* pkci = reinterpret_cast<const float*>(&Lkci[h]);
        const float* pear = reinterpret_cast<const float*>(&Lear[h]);
        const float* peai = reinterpret_cast<const float*>(&Leai[h]);
        const float* pkar = reinterpret_cast<const float*>(&Lkar[h]);
        const float* pkai = reinterpret_cast<const float*>(&Lkai[h]);

        #pragma unroll
        for (int q = 0; q < 4; q++) {
            bool first = (h == 0 && q == 0);
            float tr = ptp[q];
            float sg = __builtin_amdgcn_rcpf(1.0f + __builtin_amdgcn_exp2f(-tr * LOG2E));
            float d  = fmaf(sg, (hi - lo), lo) * 1e-9f;
            float kd = k0 * d;

            layer_stack(Mc, first, kd, pecr[q], peci[q], pkcr[q], pkci[q]);
            layer_stack(Ma, first, kd, pear[q], peai[q], pkar[q], pkai[q]);
        }
    }

    // select-free ordered reduction: P = P * shfl_xor(P, m).
    // Lanes with (j mod 2m)==0 always hold the correct left-to-right product;
    // other lanes compute unused garbage. Lane 0 ends with the full product.
    #pragma unroll
    for (int m = 1; m < GL; m <<= 1) {
        M2 Oc = shfl_m2(Mc, m);
        M2 Oa = shfl_m2(Ma, m);
        combine(Mc, Oc);
        combine(Ma, Oa);
    }

    if (j == 0) {
        const float NOUT = 1.45f;
        // denom = A + i*NOUT*B + i*C + NOUT*D  (N_IN = 1)
        f32x2 drc = Mc.A.r + NOUT * Mc.D.r - NOUT * Mc.B.i - Mc.C.i;
        f32x2 dic = Mc.A.i + NOUT * Mc.D.i + NOUT * Mc.B.r + Mc.C.r;
        f32x2 dra = Ma.A.r + NOUT * Ma.D.r - NOUT * Ma.B.i - Ma.C.i;
        f32x2 dia = Ma.A.i + NOUT * Ma.D.i + NOUT * Ma.B.r + Ma.C.r;
        f32x2 denc = drc * drc + dic * dic;
        f32x2 dena = dra * dra + dia * dia;
        // T = 4*NOUT/|den|^2 = 5.8/|den|^2 ; A = -log10(T + 1e-12)
        float Arc = -LOG10_2 * __builtin_amdgcn_logf(5.8f * __builtin_amdgcn_rcpf(denc.x) + 1e-12f);
        float Alc = -LOG10_2 * __builtin_amdgcn_logf(5.8f * __builtin_amdgcn_rcpf(denc.y) + 1e-12f);
        float Ara = -LOG10_2 * __builtin_amdgcn_logf(5.8f * __builtin_amdgcn_rcpf(dena.x) + 1e-12f);
        float Ala = -LOG10_2 * __builtin_amdgcn_logf(5.8f * __builtin_amdgcn_rcpf(dena.y) + 1e-12f);

        const float SC = (2.0f * 0.87f - 1.0f) * 32980.0f;
        out[0 * W + w] = (Alc - Arc) * SC;   // cd_c * scale
        out[1 * W + w] = (Ala - Ara) * SC;   // cd_a * scale
        out[2 * W + w] = 0.5f * (Alc + Arc); // abs_c
        out[3 * W + w] = 0.5f * (Ala + Ara); // abs_a
    }
}

extern "C" void kernel_launch(void* const* d_in, const int* in_sizes, int n_in,
                              void* d_out, int out_size, void* d_ws, size_t ws_size,
                              hipStream_t stream) {
    const float* wl     = (const float*)d_in[0];
    const float* thickP = (const float*)d_in[1];
    const float* mind   = (const float*)d_in[2];
    const float* maxd   = (const float*)d_in[3];
    const float* ecr    = (const float*)d_in[4];
    const float* eci    = (const float*)d_in[5];
    const float* kcr    = (const float*)d_in[6];
    const float* kci    = (const float*)d_in[7];
    const float* ear    = (const float*)d_in[8];
    const float* eai    = (const float*)d_in[9];
    const float* kar    = (const float*)d_in[10];
    const float* kai    = (const float*)d_in[11];
    float* out = (float*)d_out;

    int W = in_sizes[0];
    int threads = W * GL;
    int block = 256;
    int grid = (threads + block - 1) / block;
    chiral_kernel<<<grid, block, 0, stream>>>(wl, thickP, mind, maxd,
                                              ecr, eci, kcr, kci,
                                              ear, eai, kar, kai, out, W);
}

// Round 6
// 173.731 us; speedup vs baseline: 1.2492x; 1.0020x over previous
//
#include <hip/hip_runtime.h>
#include <math.h>

typedef float f32x2 __attribute__((ext_vector_type(2)));

#define LTOT 64
#define GL   16           // lanes per wavelength
#define LPL  4            // layers per lane

#define INV2PI  0.15915494309189535f
#define LOG2E   1.4426950408889634f
#define LOG10_2 0.30102999566398120f

// complex value for a packed pair of chains: lo = sigma=+1, hi = sigma=-1
struct C2 { f32x2 r, i; };
// transfer matrix in factored form [[A, iB],[iC, D]]
struct M2 { C2 A, B, C, D; };

__device__ __forceinline__ f32x2 shx(f32x2 v, int m) {
    f32x2 r;
    r.x = __shfl_xor(v.x, m);
    r.y = __shfl_xor(v.y, m);
    return r;
}

// one layer for one stack, both sigmas packed: P = P @ M_layer (or P = M if first)
__device__ __forceinline__ void layer_stack(M2& M, bool first, float kd,
                                            float er, float ei, float kr, float ki) {
    // n0 = sqrt(eps) (principal, er>0, ei>=0), inv = 1/|n0|^2 = 1/|eps|
    float h2  = fmaf(er, er, ei * ei);
    float inv = __builtin_amdgcn_rsqf(h2);       // 1/|eps|
    float mm  = h2 * inv;                        // |eps|
    float x   = 0.5f * (mm + er);
    float rx  = __builtin_amdgcn_rsqf(x);
    float n0r = x * rx;
    float n0i = 0.5f * ei * rx;

    float ar = kd * n0r, ai = kd * n0i;   // a = kd * n0
    float br = kd * kr,  bi = kd * ki;    // b = kd * kappa (|br| <= ~0.024)

    // trig of a_r (native, revolutions); small-angle polys for b_r
    float rf = __builtin_amdgcn_fractf(ar * INV2PI);
    float sa = __builtin_amdgcn_sinf(rf);
    float ca = __builtin_amdgcn_cosf(rf);
    float b2 = br * br;
    float sb = br * fmaf(b2, -0.16666667f, 1.0f);
    float cb = fmaf(b2, -0.5f, 1.0f);
    float u = sa * cb, v = ca * sb, wq = ca * cb, zq = sa * sb;

    f32x2 S, Cx, Y;
    S.x = u + v;   S.y = u - v;     // sin(ar +/- br)
    Cx.x = wq - zq; Cx.y = wq + zq; // cos(ar +/- br)
    Y.x = ai + bi; Y.y = ai - bi;   // Im(delta), |Y| <= ~0.17

    // cosh/sinh by poly (err < 3e-8 on this range)
    f32x2 y2 = Y * Y;
    f32x2 ch = (y2 * 0.041666667f + 0.5f) * y2 + 1.0f;
    f32x2 sh = Y * ((y2 * 0.0083333333f + 0.16666667f) * y2 + 1.0f);

    // cos(delta) = (Cx*ch, -S*sh) ; sin(delta) = (S*ch, Cx*sh)
    f32x2 c_r = Cx * ch;
    f32x2 c_i = -(S * sh);
    f32x2 s_r = S * ch;
    f32x2 s_i = Cx * sh;

    // q = s * conj(n0) * inv  (so m01 = i q) ; p = n0 * s (so m10 = i p)
    f32x2 q_r = (s_r * n0r + s_i * n0i) * inv;
    f32x2 q_i = (s_i * n0r - s_r * n0i) * inv;
    f32x2 p_r = s_r * n0r - s_i * n0i;
    f32x2 p_i = s_i * n0r + s_r * n0i;

    if (first) {
        M.A.r = c_r; M.A.i = c_i;
        M.B.r = q_r; M.B.i = q_i;
        M.C.r = p_r; M.C.i = p_i;
        M.D.r = c_r; M.D.i = c_i;
    } else {
        // A' = A c - B p ; B' = A q + B c ; C' = C c + D p ; D' = D c - C q
        f32x2 nAr = M.A.r*c_r - M.A.i*c_i - M.B.r*p_r + M.B.i*p_i;
        f32x2 nAi = M.A.r*c_i + M.A.i*c_r - M.B.r*p_i - M.B.i*p_r;
        f32x2 nBr = M.A.r*q_r - M.A.i*q_i + M.B.r*c_r - M.B.i*c_i;
        f32x2 nBi = M.A.r*q_i + M.A.i*q_r + M.B.r*c_i + M.B.i*c_r;
        f32x2 nCr = M.C.r*c_r - M.C.i*c_i + M.D.r*p_r - M.D.i*p_i;
        f32x2 nCi = M.C.r*c_i + M.C.i*c_r + M.D.r*p_i + M.D.i*p_r;
        f32x2 nDr = M.D.r*c_r - M.D.i*c_i - M.C.r*q_r + M.C.i*q_i;
        f32x2 nDi = M.D.r*c_i + M.D.i*c_r - M.C.r*q_i - M.C.i*q_r;
        M.A.r = nAr; M.A.i = nAi; M.B.r = nBr; M.B.i = nBi;
        M.C.r = nCr; M.C.i = nCi; M.D.r = nDr; M.D.i = nDi;
    }
}

// L = L · R in factored form:
// A = Al Ar - Bl Cr ; B = Al Br + Bl Dr ; C = Cl Ar + Dl Cr ; D = Dl Dr - Cl Br
__device__ __forceinline__ void combine(M2& L, const M2& R) {
    f32x2 nAr = L.A.r*R.A.r - L.A.i*R.A.i - L.B.r*R.C.r + L.B.i*R.C.i;
    f32x2 nAi = L.A.r*R.A.i + L.A.i*R.A.r - L.B.r*R.C.i - L.B.i*R.C.r;
    f32x2 nBr = L.A.r*R.B.r - L.A.i*R.B.i + L.B.r*R.D.r - L.B.i*R.D.i;
    f32x2 nBi = L.A.r*R.B.i + L.A.i*R.B.r + L.B.r*R.D.i + L.B.i*R.D.r;
    f32x2 nCr = L.C.r*R.A.r - L.C.i*R.A.i + L.D.r*R.C.r - L.D.i*R.C.i;
    f32x2 nCi = L.C.r*R.A.i + L.C.i*R.A.r + L.D.r*R.C.i + L.D.i*R.C.r;
    f32x2 nDr = L.D.r*R.D.r - L.D.i*R.D.i - L.C.r*R.B.r + L.C.i*R.B.i;
    f32x2 nDi = L.D.r*R.D.i + L.D.i*R.D.r - L.C.r*R.B.i - L.C.i*R.B.r;
    L.A.r = nAr; L.A.i = nAi; L.B.r = nBr; L.B.i = nBi;
    L.C.r = nCr; L.C.i = nCi; L.D.r = nDr; L.D.i = nDi;
}

__device__ __forceinline__ M2 shfl_m2(const M2& M, int m) {
    M2 R;
    R.A.r = shx(M.A.r, m); R.A.i = shx(M.A.i, m);
    R.B.r = shx(M.B.r, m); R.B.i = shx(M.B.i, m);
    R.C.r = shx(M.C.r, m); R.C.i = shx(M.C.i, m);
    R.D.r = shx(M.D.r, m); R.D.i = shx(M.D.i, m);
    return R;
}

__global__ __launch_bounds__(256, 4) void chiral_kernel(
    const float* __restrict__ wl,  const float* __restrict__ thickP,
    const float* __restrict__ mindp, const float* __restrict__ maxdp,
    const float* __restrict__ ecr, const float* __restrict__ eci,
    const float* __restrict__ kcr, const float* __restrict__ kci,
    const float* __restrict__ ear, const float* __restrict__ eai,
    const float* __restrict__ kar, const float* __restrict__ kai,
    float* __restrict__ out, int W)
{
    int t = blockIdx.x * blockDim.x + threadIdx.x;
    int w = t >> 4;      // one 16-lane group per wavelength
    int j = t & 15;      // lane owns layers 4j..4j+3
    if (w >= W) return;

    size_t base = (size_t)w * LTOT + (size_t)(LPL * j);

    // ---- prefetch: exactly 9 float4 per thread (fits in registers) ----
    float4 Ltp  = *reinterpret_cast<const float4*>(thickP + LPL * j);
    float4 Lecr = *reinterpret_cast<const float4*>(ecr + base);
    float4 Leci = *reinterpret_cast<const float4*>(eci + base);
    float4 Lkcr = *reinterpret_cast<const float4*>(kcr + base);
    float4 Lkci = *reinterpret_cast<const float4*>(kci + base);
    float4 Lear = *reinterpret_cast<const float4*>(ear + base);
    float4 Leai = *reinterpret_cast<const float4*>(eai + base);
    float4 Lkar = *reinterpret_cast<const float4*>(kar + base);
    float4 Lkai = *reinterpret_cast<const float4*>(kai + base);

    float lo = mindp[0], hi = maxdp[0];
    float k0 = 6.2831852e6f * __builtin_amdgcn_rcpf(wl[w]);

    const float* ptp  = reinterpret_cast<const float*>(&Ltp);
    const float* pecr = reinterpret_cast<const float*>(&Lecr);
    const float* peci = reinterpret_cast<const float*>(&Leci);
    const float* pkcr = reinterpret_cast<const float*>(&Lkcr);
    const float* pkci = reinterpret_cast<const float*>(&Lkci);
    const float* pear = reinterpret_cast<const float*>(&Lear);
    const float* peai = reinterpret_cast<const float*>(&Leai);
    const float* pkar = reinterpret_cast<const float*>(&Lkar);
    const float* pkai = reinterpret_cast<const float*>(&Lkai);

    M2 Mc, Ma;   // stack c, stack a (each holds sigma +/- packed)

    #pragma unroll
    for (int q = 0; q < LPL; q++) {
        bool first = (q == 0);
        float tr = ptp[q];
        float sg = __builtin_amdgcn_rcpf(1.0f + __builtin_amdgcn_exp2f(-tr * LOG2E));
        float d  = fmaf(sg, (hi - lo), lo) * 1e-9f;
        float kd = k0 * d;

        layer_stack(Mc, first, kd, pecr[q], peci[q], pkcr[q], pkci[q]);
        layer_stack(Ma, first, kd, pear[q], peai[q], pkar[q], pkai[q]);
    }

    // select-free ordered reduction: P = P * shfl_xor(P, m).
    // Lanes with (j mod 2m)==0 hold the correct left-to-right product;
    // lane 0 ends with the full 64-layer product.
    #pragma unroll
    for (int m = 1; m < GL; m <<= 1) {
        M2 Oc = shfl_m2(Mc, m);
        M2 Oa = shfl_m2(Ma, m);
        combine(Mc, Oc);
        combine(Ma, Oa);
    }

    if (j == 0) {
        const float NOUT = 1.45f;
        // denom = A + i*NOUT*B + i*C + NOUT*D  (N_IN = 1)
        f32x2 drc = Mc.A.r + NOUT * Mc.D.r - NOUT * Mc.B.i - Mc.C.i;
        f32x2 dic = Mc.A.i + NOUT * Mc.D.i + NOUT * Mc.B.r + Mc.C.r;
        f32x2 dra = Ma.A.r + NOUT * Ma.D.r - NOUT * Ma.B.i - Ma.C.i;
        f32x2 dia = Ma.A.i + NOUT * Ma.D.i + NOUT * Ma.B.r + Ma.C.r;
        f32x2 denc = drc * drc + dic * dic;
        f32x2 dena = dra * dra + dia * dia;
        // T = 4*NOUT/|den|^2 = 5.8/|den|^2 ; A = -log10(T + 1e-12)
        float Arc = -LOG10_2 * __builtin_amdgcn_logf(5.8f * __builtin_amdgcn_rcpf(denc.x) + 1e-12f);
        float Alc = -LOG10_2 * __builtin_amdgcn_logf(5.8f * __builtin_amdgcn_rcpf(denc.y) + 1e-12f);
        float Ara = -LOG10_2 * __builtin_amdgcn_logf(5.8f * __builtin_amdgcn_rcpf(dena.x) + 1e-12f);
        float Ala = -LOG10_2 * __builtin_amdgcn_logf(5.8f * __builtin_amdgcn_rcpf(dena.y) + 1e-12f);

        const float SC = (2.0f * 0.87f - 1.0f) * 32980.0f;
        out[0 * W + w] = (Alc - Arc) * SC;   // cd_c * scale
        out[1 * W + w] = (Ala - Ara) * SC;   // cd_a * scale
        out[2 * W + w] = 0.5f * (Alc + Arc); // abs_c
        out[3 * W + w] = 0.5f * (Ala + Ara); // abs_a
    }
}

extern "C" void kernel_launch(void* const* d_in, const int* in_sizes, int n_in,
                              void* d_out, int out_size, void* d_ws, size_t ws_size,
                              hipStream_t stream) {
    const float* wl     = (const float*)d_in[0];
    const float* thickP = (const float*)d_in[1];
    const float* mind   = (const float*)d_in[2];
    const float* maxd   = (const float*)d_in[3];
    const float* ecr    = (const float*)d_in[4];
    const float* eci    = (const float*)d_in[5];
    const float* kcr    = (const float*)d_in[6];
    const float* kci    = (const float*)d_in[7];
    const float* ear    = (const float*)d_in[8];
    const float* eai    = (const float*)d_in[9];
    const float* kar    = (const float*)d_in[10];
    const float* kai    = (const float*)d_in[11];
    float* out = (float*)d_out;

    int W = in_sizes[0];
    int threads = W * GL;
    int block = 256;
    int grid = (threads + block - 1) / block;
    chiral_kernel<<<grid, block, 0, stream>>>(wl, thickP, mind, maxd,
                                              ecr, eci, kcr, kci,
                                              ear, eai, kar, kai, out, W);
}